// Round 6
// baseline (249.191 us; speedup 1.0000x reference)
//
#include <hip/hip_runtime.h>

static constexpr int NROWS = 32768;
static constexpr int FIN   = 1024;
static constexpr int FOUT  = 512;
static constexpr int NREP  = 16;     // u accumulator replicas

// ws layout (total ~340 KB of 512 MiB):
//   double e[32768]       : unnormalized exp(scores)        (256 KB)
//   double hpart[1024]    : h[k] * (W@a1)[k]                (8 KB)
//   double zpart[1024]    : per-k2a-block partial of Z      (8 KB)
//   float  v[1024]        : W @ a2                          (4 KB)
//   float  u16[16][1024]  : replicated u accumulators       (64 KB)
//
// d_out layout: [0:512) out fp32 | [512:33280) attention2 as 0.0/1.0

// ---------------------------------------------------------------------------
// K1: one wave per k (1024 waves). No atomics. Blocks 0..15 also zero u16.
// ---------------------------------------------------------------------------
__global__ __launch_bounds__(256) void k1_prep(const float* __restrict__ W,
                                               const float* __restrict__ a,
                                               const float* __restrict__ h,
                                               float* __restrict__ v,
                                               double* __restrict__ hpart,
                                               float* __restrict__ u16) {
    if (blockIdx.x < 16) {
        ((float4*)u16)[blockIdx.x * 256 + threadIdx.x] =
            make_float4(0.f, 0.f, 0.f, 0.f);
    }

    const int k    = (blockIdx.x * blockDim.x + threadIdx.x) >> 6;  // 0..1023
    const int lane = threadIdx.x & 63;

    const float4* Wrow = (const float4*)(W + (size_t)k * FOUT);
    float4 w0 = Wrow[lane];
    float4 w1 = Wrow[64 + lane];

    const float4* a4 = (const float4*)a;
    float4 a1_0 = a4[lane];
    float4 a1_1 = a4[64 + lane];
    float4 a2_0 = a4[128 + lane];
    float4 a2_1 = a4[192 + lane];

    double d1 = (double)w0.x * a1_0.x + (double)w0.y * a1_0.y +
                (double)w0.z * a1_0.z + (double)w0.w * a1_0.w +
                (double)w1.x * a1_1.x + (double)w1.y * a1_1.y +
                (double)w1.z * a1_1.z + (double)w1.w * a1_1.w;
    double d2 = (double)w0.x * a2_0.x + (double)w0.y * a2_0.y +
                (double)w0.z * a2_0.z + (double)w0.w * a2_0.w +
                (double)w1.x * a2_1.x + (double)w1.y * a2_1.y +
                (double)w1.z * a2_1.z + (double)w1.w * a2_1.w;

    #pragma unroll
    for (int off = 32; off; off >>= 1) {
        d1 += __shfl_xor(d1, off);
        d2 += __shfl_xor(d2, off);
    }
    if (lane == 0) {
        v[k]     = (float)d2;
        hpart[k] = (double)h[k] * d1;
    }
}

// ---------------------------------------------------------------------------
// K2a: scores only. 1024 blocks x 4 waves, 8 rows/wave in 2 batches of 4.
// 4 independent dot/butterfly/exp chains per batch -> latency overlap.
// No u accumulation (that's k2b). ev is wave-uniform after the butterfly;
// zacc needs NO further reduction (the x64 bug of r2/r3).
// ---------------------------------------------------------------------------
__global__ __launch_bounds__(256) void k2a_scores(const float* __restrict__ adj,
                                                  const float* __restrict__ v,
                                                  const double* __restrict__ hpart,
                                                  double* __restrict__ e,
                                                  double* __restrict__ zpart) {
    __shared__ double zls[4];

    const int wave  = threadIdx.x >> 6;
    const int lane  = threadIdx.x & 63;
    const int gwave = blockIdx.x * 4 + wave;          // 0..4095

    // c0 = sum(hpart), identical order everywhere -> bitwise-identical
    double c0 = 0.0;
    #pragma unroll
    for (int j = 0; j < 16; ++j) c0 += hpart[j * 64 + lane];
    #pragma unroll
    for (int off = 32; off; off >>= 1) c0 += __shfl_xor(c0, off);

    const float4* v4 = (const float4*)v;
    float4 vf[4];
    #pragma unroll
    for (int q = 0; q < 4; ++q) vf[q] = v4[q * 64 + lane];

    double zacc = 0.0;
    const int row0 = gwave * 8;

    #pragma unroll
    for (int b = 0; b < 2; ++b) {
        const int r0 = row0 + b * 4;

        // 16 loads issued before any dependent math
        float4 d[4][4];
        #pragma unroll
        for (int r = 0; r < 4; ++r) {
            const float4* arow = (const float4*)(adj + (size_t)(r0 + r) * FIN);
            #pragma unroll
            for (int q = 0; q < 4; ++q) d[r][q] = arow[q * 64 + lane];
        }

        // 4 independent f64 dot chains
        double dot[4];
        #pragma unroll
        for (int r = 0; r < 4; ++r) {
            double t = 0.0;
            #pragma unroll
            for (int q = 0; q < 4; ++q) {
                t += (double)d[r][q].x * vf[q].x + (double)d[r][q].y * vf[q].y +
                     (double)d[r][q].z * vf[q].z + (double)d[r][q].w * vf[q].w;
            }
            dot[r] = t;
        }

        // 4 interleaved butterflies (independent LDS-pipe chains)
        #pragma unroll
        for (int off = 32; off; off >>= 1) {
            #pragma unroll
            for (int r = 0; r < 4; ++r) dot[r] += __shfl_xor(dot[r], off);
        }

        // 4 independent exp chains
        double ev[4];
        #pragma unroll
        for (int r = 0; r < 4; ++r) {
            double s = c0 + dot[r];
            if (s < 0.0) s *= 0.1;     // leaky_relu(0.1)
            ev[r] = exp(s);            // wave-uniform
            zacc += ev[r];
        }
        if (lane == 0) {
            e[r0 + 0] = ev[0];
            e[r0 + 1] = ev[1];
            e[r0 + 2] = ev[2];
            e[r0 + 3] = ev[3];
        }
    }

    if (lane == 0) zls[wave] = zacc;   // already wave-complete
    __syncthreads();
    if (threadIdx.x == 0) zpart[blockIdx.x] = zls[0] + zls[1] + zls[2] + zls[3];
}

// ---------------------------------------------------------------------------
// K2b: u accumulation. 1024 blocks x 4 waves, 8 rows/wave, 2-row batches.
// Pure streaming FMA over adj (L3-hot), no cross-lane ops in the loop.
// Block LDS reduce then 4 fp32 atomics/thread into replica blockIdx&15
// (same-address chain length 64).
// ---------------------------------------------------------------------------
__global__ __launch_bounds__(256) void k2b_u(const float* __restrict__ adj,
                                             const double* __restrict__ e,
                                             float* __restrict__ u16) {
    __shared__ float uls[4][1024];

    const int wave  = threadIdx.x >> 6;
    const int lane  = threadIdx.x & 63;
    const int gwave = blockIdx.x * 4 + wave;
    const int row0  = gwave * 8;

    float uacc[4][4] = {};

    #pragma unroll
    for (int r = 0; r < 8; r += 2) {
        const float4* arow0 = (const float4*)(adj + (size_t)(row0 + r) * FIN);
        const float4* arow1 = (const float4*)(adj + (size_t)(row0 + r + 1) * FIN);
        float4 d0[4], d1[4];
        #pragma unroll
        for (int q = 0; q < 4; ++q) d0[q] = arow0[q * 64 + lane];
        #pragma unroll
        for (int q = 0; q < 4; ++q) d1[q] = arow1[q * 64 + lane];

        const float e0 = (float)e[row0 + r];
        const float e1 = (float)e[row0 + r + 1];

        #pragma unroll
        for (int q = 0; q < 4; ++q) {
            uacc[q][0] += e0 * d0[q].x;
            uacc[q][1] += e0 * d0[q].y;
            uacc[q][2] += e0 * d0[q].z;
            uacc[q][3] += e0 * d0[q].w;
        }
        #pragma unroll
        for (int q = 0; q < 4; ++q) {
            uacc[q][0] += e1 * d1[q].x;
            uacc[q][1] += e1 * d1[q].y;
            uacc[q][2] += e1 * d1[q].z;
            uacc[q][3] += e1 * d1[q].w;
        }
    }

    float4* uls4w = (float4*)&uls[wave][0];
    #pragma unroll
    for (int q = 0; q < 4; ++q)
        uls4w[q * 64 + lane] = make_float4(uacc[q][0], uacc[q][1], uacc[q][2], uacc[q][3]);

    __syncthreads();

    const int t = threadIdx.x;
    const float4* uls4 = (const float4*)uls;
    float4 s0 = uls4[t];
    float4 s1 = uls4[256 + t];
    float4 s2 = uls4[512 + t];
    float4 s3 = uls4[768 + t];

    float* urep = u16 + (size_t)(blockIdx.x & (NREP - 1)) * 1024 + 4 * t;
    unsafeAtomicAdd(&urep[0], s0.x + s1.x + s2.x + s3.x);
    unsafeAtomicAdd(&urep[1], s0.y + s1.y + s2.y + s3.y);
    unsafeAtomicAdd(&urep[2], s0.z + s1.z + s2.z + s3.z);
    unsafeAtomicAdd(&urep[3], s0.w + s1.w + s2.w + s3.w);
}

// ---------------------------------------------------------------------------
// Deterministic Z from zpart (identical order in every block).
// ---------------------------------------------------------------------------
__device__ __forceinline__ double block_reduce_Z(const double* __restrict__ zpart,
                                                 double* zs) {
    const int t = threadIdx.x;
    zs[t] = zpart[t] + zpart[256 + t] + zpart[512 + t] + zpart[768 + t];
    __syncthreads();
    for (int st = 128; st > 0; st >>= 1) {
        if (t < st) zs[t] += zs[t + st];
        __syncthreads();
    }
    double Z = zs[0];
    __syncthreads();
    return Z;
}

// ---------------------------------------------------------------------------
// K3: blocks 0..15   -> out[0:512] = (u/Z) @ W1
//     blocks 16..143 -> out[512+i] = (N*e_i > Z) ? 1 : 0
// ---------------------------------------------------------------------------
__global__ __launch_bounds__(256) void k3_final(const double* __restrict__ e,
                                                const double* __restrict__ zpart,
                                                const float* __restrict__ u16,
                                                const float* __restrict__ W1,
                                                float* __restrict__ out) {
    __shared__ double zs[256];
    const double Z = block_reduce_Z(zpart, zs);
    const int t = threadIdx.x;

    if (blockIdx.x < 16) {
        __shared__ float us[1024];
        __shared__ float red[8][32];

        #pragma unroll
        for (int g = 0; g < 4; ++g) {
            const int k = g * 256 + t;
            float s = 0.f;
            #pragma unroll
            for (int rep = 0; rep < NREP; ++rep) s += u16[rep * 1024 + k];
            us[k] = s;
        }
        __syncthreads();

        const int cl  = t & 31;
        const int kg  = t >> 5;
        const int col = blockIdx.x * 32 + cl;
        float acc = 0.f;
        #pragma unroll 4
        for (int kk = 0; kk < 128; ++kk) {
            const int k = kg * 128 + kk;
            acc += us[k] * W1[(size_t)k * FOUT + col];
        }
        red[kg][cl] = acc;
        __syncthreads();
        if (t < 32) {
            float tot = 0.f;
            #pragma unroll
            for (int g = 0; g < 8; ++g) tot += red[g][t];
            out[blockIdx.x * 32 + t] = (float)((double)tot / Z);
        }
    } else {
        const int i = (blockIdx.x - 16) * 256 + t;
        out[FOUT + i] = (e[i] * (double)NROWS > Z) ? 1.0f : 0.0f;
    }
}

extern "C" void kernel_launch(void* const* d_in, const int* in_sizes, int n_in,
                              void* d_out, int out_size, void* d_ws, size_t ws_size,
                              hipStream_t stream) {
    const float* h   = (const float*)d_in[0];   // (1, 1024)
    const float* adj = (const float*)d_in[1];   // (32768, 1024)
    const float* W   = (const float*)d_in[2];   // (1024, 512)
    const float* a   = (const float*)d_in[3];   // (1024, 1)
    const float* W1  = (const float*)d_in[4];   // (1024, 512)
    float* out = (float*)d_out;

    double* e     = (double*)d_ws;              // [32768]
    double* hpart = e + NROWS;                  // [1024]
    double* zpart = hpart + 1024;               // [1024]
    float*  v     = (float*)(zpart + 1024);     // [1024]
    float*  u16   = v + 1024;                   // [16][1024]

    k1_prep<<<dim3(256),    dim3(256), 0, stream>>>(W, a, h, v, hpart, u16);
    k2a_scores<<<dim3(1024), dim3(256), 0, stream>>>(adj, v, hpart, e, zpart);
    k2b_u<<<dim3(1024),     dim3(256), 0, stream>>>(adj, e, u16);
    k3_final<<<dim3(144),   dim3(256), 0, stream>>>(e, zpart, u16, W1, out);
}

// Round 7
// 225.536 us; speedup vs baseline: 1.1049x; 1.1049x over previous
//
#include <hip/hip_runtime.h>

static constexpr int NROWS = 32768;
static constexpr int FIN   = 1024;
static constexpr int FOUT  = 512;
static constexpr int NREP  = 16;     // u accumulator replicas

// ws layout (total ~340 KB of 512 MiB):
//   double e[32768]       : unnormalized exp(scores)        (256 KB)
//   double hpart[1024]    : h[k] * (W@a1)[k]                (8 KB)
//   double zpart[1024]    : per-K2-block partial of Z       (8 KB)
//   float  v[1024]        : W @ a2                          (4 KB)
//   float  u16[16][1024]  : replicated u accumulators       (64 KB)
//
// d_out layout: [0:512) out fp32 | [512:33280) attention2 as 0.0/1.0
//
// Structure rationale (measured over rounds 1-6):
//  - Both big GEMMs collapse by associativity: scores = adj@(W@a2)+c0,
//    out = ((att@adj)/Z)@W1 — total compulsory traffic = one 128 MiB adj read.
//  - Single fused adj pass (k2) is memory-bound ~24-28 us; splitting into
//    scores+accum passes costs exactly one extra adj read (+23.8 us, r6).
//  - Atomic chains kept short: block-level LDS reduce then 16-way replicated
//    u accumulators (chain length 64); single-address fp64 chains (r1: 419 us)
//    eliminated via hpart/zpart deterministic reductions.
//  - ev is wave-uniform after the dot butterfly — zacc must NOT be
//    butterfly-reduced again (x64 Z bug, r2/r3).

// ---------------------------------------------------------------------------
// K1: one wave per k (1024 waves). No atomics. Blocks 0..15 also zero u16.
// ---------------------------------------------------------------------------
__global__ __launch_bounds__(256) void k1_prep(const float* __restrict__ W,
                                               const float* __restrict__ a,
                                               const float* __restrict__ h,
                                               float* __restrict__ v,
                                               double* __restrict__ hpart,
                                               float* __restrict__ u16) {
    if (blockIdx.x < 16) {
        ((float4*)u16)[blockIdx.x * 256 + threadIdx.x] =
            make_float4(0.f, 0.f, 0.f, 0.f);
    }

    const int k    = (blockIdx.x * blockDim.x + threadIdx.x) >> 6;  // 0..1023
    const int lane = threadIdx.x & 63;

    const float4* Wrow = (const float4*)(W + (size_t)k * FOUT);
    float4 w0 = Wrow[lane];
    float4 w1 = Wrow[64 + lane];

    const float4* a4 = (const float4*)a;
    float4 a1_0 = a4[lane];
    float4 a1_1 = a4[64 + lane];
    float4 a2_0 = a4[128 + lane];
    float4 a2_1 = a4[192 + lane];

    double d1 = (double)w0.x * a1_0.x + (double)w0.y * a1_0.y +
                (double)w0.z * a1_0.z + (double)w0.w * a1_0.w +
                (double)w1.x * a1_1.x + (double)w1.y * a1_1.y +
                (double)w1.z * a1_1.z + (double)w1.w * a1_1.w;
    double d2 = (double)w0.x * a2_0.x + (double)w0.y * a2_0.y +
                (double)w0.z * a2_0.z + (double)w0.w * a2_0.w +
                (double)w1.x * a2_1.x + (double)w1.y * a2_1.y +
                (double)w1.z * a2_1.z + (double)w1.w * a2_1.w;

    #pragma unroll
    for (int off = 32; off; off >>= 1) {
        d1 += __shfl_xor(d1, off);
        d2 += __shfl_xor(d2, off);
    }
    if (lane == 0) {
        v[k]     = (float)d2;
        hpart[k] = (double)h[k] * d1;
    }
}

// ---------------------------------------------------------------------------
// K2: 1024 blocks x 256 threads (4096 waves, 8 rows/wave). Single adj pass
// (memory-bound, ~24-28 us). Per-block LDS reduce of u, then 4 fp32
// atomics/thread into replica u16[blockIdx&15][:] -> chain length 64.
// c0 reduced redundantly per wave from hpart (deterministic order).
// ---------------------------------------------------------------------------
__global__ __launch_bounds__(256) void k2_main(const float* __restrict__ adj,
                                               const float* __restrict__ v,
                                               const double* __restrict__ hpart,
                                               double* __restrict__ e,
                                               float* __restrict__ u16,   // [16][1024]
                                               double* __restrict__ zpart) {
    __shared__ float  uls[4][1024];
    __shared__ double zls[4];

    const int wave  = threadIdx.x >> 6;               // 0..3
    const int lane  = threadIdx.x & 63;
    const int gwave = blockIdx.x * 4 + wave;          // 0..4095

    // c0 = sum(hpart), identical order in every wave -> bitwise-identical
    double c0 = 0.0;
    #pragma unroll
    for (int j = 0; j < 16; ++j) c0 += hpart[j * 64 + lane];
    #pragma unroll
    for (int off = 32; off; off >>= 1) c0 += __shfl_xor(c0, off);

    const float4* v4 = (const float4*)v;
    float4 vf[4];
    #pragma unroll
    for (int q = 0; q < 4; ++q) vf[q] = v4[q * 64 + lane];

    float  uacc[4][4] = {};
    double zacc = 0.0;   // wave-uniform

    const int row0 = gwave * 8;
    for (int r = 0; r < 8; ++r) {
        const int row = row0 + r;
        const float4* arow = (const float4*)(adj + (size_t)row * FIN);
        float4 d[4];
        #pragma unroll
        for (int q = 0; q < 4; ++q) d[q] = arow[q * 64 + lane];

        double dot = 0.0;
        #pragma unroll
        for (int q = 0; q < 4; ++q) {
            dot += (double)d[q].x * vf[q].x + (double)d[q].y * vf[q].y +
                   (double)d[q].z * vf[q].z + (double)d[q].w * vf[q].w;
        }
        #pragma unroll
        for (int off = 32; off; off >>= 1) dot += __shfl_xor(dot, off);

        double s = c0 + dot;
        if (s < 0.0) s *= 0.1;       // leaky_relu(0.1)
        const double ev = exp(s);    // wave-uniform
        zacc += ev;
        if (lane == 0) e[row] = ev;

        const float evf = (float)ev;
        #pragma unroll
        for (int q = 0; q < 4; ++q) {
            uacc[q][0] += evf * d[q].x;
            uacc[q][1] += evf * d[q].y;
            uacc[q][2] += evf * d[q].z;
            uacc[q][3] += evf * d[q].w;
        }
    }

    // per-wave u partial -> LDS (conflict-free b128 writes)
    float4* uls4w = (float4*)&uls[wave][0];
    #pragma unroll
    for (int q = 0; q < 4; ++q)
        uls4w[q * 64 + lane] = make_float4(uacc[q][0], uacc[q][1], uacc[q][2], uacc[q][3]);

    if (lane == 0) zls[wave] = zacc;   // zacc already wave-complete

    __syncthreads();

    // cross-wave reduce; thread t owns cols 4t..4t+3
    const int t = threadIdx.x;
    const float4* uls4 = (const float4*)uls;
    float4 s0 = uls4[t];
    float4 s1 = uls4[256 + t];
    float4 s2 = uls4[512 + t];
    float4 s3 = uls4[768 + t];

    float* urep = u16 + (size_t)(blockIdx.x & (NREP - 1)) * 1024 + 4 * t;
    unsafeAtomicAdd(&urep[0], s0.x + s1.x + s2.x + s3.x);
    unsafeAtomicAdd(&urep[1], s0.y + s1.y + s2.y + s3.y);
    unsafeAtomicAdd(&urep[2], s0.z + s1.z + s2.z + s3.z);
    unsafeAtomicAdd(&urep[3], s0.w + s1.w + s2.w + s3.w);

    if (t == 0) zpart[blockIdx.x] = zls[0] + zls[1] + zls[2] + zls[3];
}

// ---------------------------------------------------------------------------
// Deterministic Z from zpart (identical order in every block).
// ---------------------------------------------------------------------------
__device__ __forceinline__ double block_reduce_Z(const double* __restrict__ zpart,
                                                 double* zs) {
    const int t = threadIdx.x;
    zs[t] = zpart[t] + zpart[256 + t] + zpart[512 + t] + zpart[768 + t];
    __syncthreads();
    for (int st = 128; st > 0; st >>= 1) {
        if (t < st) zs[t] += zs[t + st];
        __syncthreads();
    }
    double Z = zs[0];
    __syncthreads();
    return Z;
}

// ---------------------------------------------------------------------------
// K3 (fused): blocks 0..15   -> out[0:512] = (u/Z) @ W1
//             blocks 16..143 -> out[512+i] = (N*e_i > Z) ? 1 : 0
// ---------------------------------------------------------------------------
__global__ __launch_bounds__(256) void k3_final(const double* __restrict__ e,
                                                const double* __restrict__ zpart,
                                                const float* __restrict__ u16,
                                                const float* __restrict__ W1,
                                                float* __restrict__ out) {
    __shared__ double zs[256];
    const double Z = block_reduce_Z(zpart, zs);
    const int t = threadIdx.x;

    if (blockIdx.x < 16) {
        __shared__ float us[1024];
        __shared__ float red[8][32];

        // us[k] = sum over 16 replicas
        #pragma unroll
        for (int g = 0; g < 4; ++g) {
            const int k = g * 256 + t;
            float s = 0.f;
            #pragma unroll
            for (int rep = 0; rep < NREP; ++rep) s += u16[rep * 1024 + k];
            us[k] = s;
        }
        __syncthreads();

        const int cl  = t & 31;               // col within 32-col slab
        const int kg  = t >> 5;               // 0..7 k-group
        const int col = blockIdx.x * 32 + cl;
        float acc = 0.f;
        #pragma unroll 4
        for (int kk = 0; kk < 128; ++kk) {
            const int k = kg * 128 + kk;
            acc += us[k] * W1[(size_t)k * FOUT + col];
        }
        red[kg][cl] = acc;
        __syncthreads();
        if (t < 32) {
            float tot = 0.f;
            #pragma unroll
            for (int g = 0; g < 8; ++g) tot += red[g][t];
            out[blockIdx.x * 32 + t] = (float)((double)tot / Z);
        }
    } else {
        const int i = (blockIdx.x - 16) * 256 + t;   // 0..32767
        out[FOUT + i] = (e[i] * (double)NROWS > Z) ? 1.0f : 0.0f;
    }
}

extern "C" void kernel_launch(void* const* d_in, const int* in_sizes, int n_in,
                              void* d_out, int out_size, void* d_ws, size_t ws_size,
                              hipStream_t stream) {
    const float* h   = (const float*)d_in[0];   // (1, 1024)
    const float* adj = (const float*)d_in[1];   // (32768, 1024)
    const float* W   = (const float*)d_in[2];   // (1024, 512)
    const float* a   = (const float*)d_in[3];   // (1024, 1)
    const float* W1  = (const float*)d_in[4];   // (1024, 512)
    float* out = (float*)d_out;

    double* e     = (double*)d_ws;              // [32768]
    double* hpart = e + NROWS;                  // [1024]
    double* zpart = hpart + 1024;               // [1024]
    float*  v     = (float*)(zpart + 1024);     // [1024]
    float*  u16   = v + 1024;                   // [16][1024]

    k1_prep<<<dim3(256),  dim3(256), 0, stream>>>(W, a, h, v, hpart, u16);
    k2_main<<<dim3(1024), dim3(256), 0, stream>>>(adj, v, hpart, e, u16, zpart);
    k3_final<<<dim3(144), dim3(256), 0, stream>>>(e, zpart, u16, W1, out);
}